// Round 16
// baseline (116.850 us; speedup 1.0000x reference)
//
#include <hip/hip_runtime.h>
#include <math.h>

// Problem constants
#define NB    16            // batches
#define NPB   (512*512)     // elements per batch
#define NBINS 64
#define MMB   64            // minmax blocks per batch (grid 1024 = 4/CU)
#define CB    64            // hist chunks per (tensor,batch) -> grid 2*16*64 = 2048
#define EPSF  1e-8f
#define QF    0.84932180517f   // sqrt(0.5*log2(e)); exp(-d^2/2) = exp2(-(q*d)^2)
#define L2E   1.44269504089f   // log2(e)
#define LN2   0.69314718056f
#define K16   1.12535175e-7f   // e^-16 (anchor-2 rate adjust)
#define K16I  8886110.5f       // e^+16

// ws layout: mmn[1024] | mmx[1024] | hist[2][16][64]

// ---------- pass 1: per-batch block-level min/max (also zeroes hist) ----------
__global__ __launch_bounds__(256) void minmax_k(const float4* __restrict__ tgt,
                                                float* __restrict__ mmn,
                                                float* __restrict__ mmx,
                                                float* __restrict__ hist) {
    const int batch = blockIdx.x / MMB, sub = blockIdx.x % MMB;
    if (sub == 0 && threadIdx.x < 128) {
        const int tens = threadIdx.x >> 6, lane = threadIdx.x & 63;
        hist[(tens * NB + batch) * NBINS + lane] = 0.0f;
    }

    const int F4 = NPB / 4 / MMB;              // 1024 float4 per block
    const float4* p = tgt + (size_t)batch * (NPB / 4) + (size_t)sub * F4;
    float mn = 3.4e38f, mx = -3.4e38f;
    #pragma unroll
    for (int i = 0; i < F4 / 256; ++i) {       // 4 iterations
        float4 v = p[i * 256 + threadIdx.x];
        mn = fminf(mn, fminf(fminf(v.x, v.y), fminf(v.z, v.w)));
        mx = fmaxf(mx, fmaxf(fmaxf(v.x, v.y), fmaxf(v.z, v.w)));
    }
    #pragma unroll
    for (int o = 1; o < 64; o <<= 1) {
        mn = fminf(mn, __shfl_xor(mn, o));
        mx = fmaxf(mx, __shfl_xor(mx, o));
    }
    __shared__ float smn[4], smx[4];
    const int wave = threadIdx.x >> 6, lane = threadIdx.x & 63;
    if (lane == 0) { smn[wave] = mn; smx[wave] = mx; }
    __syncthreads();
    if (threadIdx.x == 0) {
        mmn[blockIdx.x] = fminf(fminf(smn[0], smn[1]), fminf(smn[2], smn[3]));
        mmx[blockIdx.x] = fmaxf(fmaxf(smx[0], smx[1]), fmaxf(smx[2], smx[3]));
    }
}

// ---------- paired-point update of 32 bins via two anchors sharing r/ri ----------
// Two points a,b interleaved: independent T chains (Ta*=ra, Tb*=rb) break the
// serial 4-cyc mul-latency chain; the shared bin constant folds both into ONE
// accumulate: acc[j] = fma(Ta+Tb, C_j, acc[j]).
// NOTE: needs a VGPR budget >= ~70 — at (256,8) the 64-VGPR cap spilled acc[]
// to scratch (R14: WRITE_SIZE 1->121 MB, hist 44->74 us). (256,4/6) is safe
// (52 VGPR measured at (256,4)).
// Anchors at kwb+8 (bins 0..15) and kwb+24 (bins 16..31); E(m+i)=A*rho^i*C_i,
// C_i = e^{-i^2/2} literals. d clamped to [-30,46]: outside, both A==0 before
// any rho power overflows (max ~9e19 finite) -> far points contribute exact 0.
__device__ __forceinline__ void pair32(float xa, float xb, float s64, float bk8,
                                       float* __restrict__ acc) {
    const float C1 = 0.60653065971f,    C2 = 0.13533528324f,
                C3 = 0.01110899654f,    C4 = 3.35462627903e-4f,
                C5 = 3.72665317208e-6f, C6 = 1.52299797447e-8f,
                C7 = 2.28973484833e-11f, C8 = 1.26641655490e-14f;
    float da  = fmaf(xa, s64, bk8),  db  = fmaf(xb, s64, bk8);
    float ca  = __builtin_amdgcn_fmed3f(da, -30.0f, 46.0f);
    float cb  = __builtin_amdgcn_fmed3f(db, -30.0f, 46.0f);
    float ya  = ca * L2E,            yb  = cb * L2E;
    float ra  = __builtin_amdgcn_exp2f(ya),  rb  = __builtin_amdgcn_exp2f(yb);
    float ia  = __builtin_amdgcn_exp2f(-ya), ib  = __builtin_amdgcn_exp2f(-yb);
    float t1a = ca * QF,             t1b = cb * QF;
    float A1a = __builtin_amdgcn_exp2f(-(t1a * t1a));
    float A1b = __builtin_amdgcn_exp2f(-(t1b * t1b));
    float t2a = fmaf(ca, QF, -16.0f * QF), t2b = fmaf(cb, QF, -16.0f * QF);
    float A2a = __builtin_amdgcn_exp2f(-(t2a * t2a));
    float A2b = __builtin_amdgcn_exp2f(-(t2b * t2b));
    float r2a = ra * K16,  r2b = rb * K16;
    float i2a = ia * K16I, i2b = ib * K16I;
    // anchor1: bins 0..15 (mid 8)
    float Ta = A1a, Tb = A1b, Ua = A1a, Ub = A1b;
    acc[8] += A1a + A1b;
    Ta *= ra; Tb *= rb; acc[9]  = fmaf(Ta + Tb, C1, acc[9]);
    Ta *= ra; Tb *= rb; acc[10] = fmaf(Ta + Tb, C2, acc[10]);
    Ta *= ra; Tb *= rb; acc[11] = fmaf(Ta + Tb, C3, acc[11]);
    Ta *= ra; Tb *= rb; acc[12] = fmaf(Ta + Tb, C4, acc[12]);
    Ta *= ra; Tb *= rb; acc[13] = fmaf(Ta + Tb, C5, acc[13]);
    Ta *= ra; Tb *= rb; acc[14] = fmaf(Ta + Tb, C6, acc[14]);
    Ta *= ra; Tb *= rb; acc[15] = fmaf(Ta + Tb, C7, acc[15]);
    Ua *= ia; Ub *= ib; acc[7]  = fmaf(Ua + Ub, C1, acc[7]);
    Ua *= ia; Ub *= ib; acc[6]  = fmaf(Ua + Ub, C2, acc[6]);
    Ua *= ia; Ub *= ib; acc[5]  = fmaf(Ua + Ub, C3, acc[5]);
    Ua *= ia; Ub *= ib; acc[4]  = fmaf(Ua + Ub, C4, acc[4]);
    Ua *= ia; Ub *= ib; acc[3]  = fmaf(Ua + Ub, C5, acc[3]);
    Ua *= ia; Ub *= ib; acc[2]  = fmaf(Ua + Ub, C6, acc[2]);
    Ua *= ia; Ub *= ib; acc[1]  = fmaf(Ua + Ub, C7, acc[1]);
    Ua *= ia; Ub *= ib; acc[0]  = fmaf(Ua + Ub, C8, acc[0]);
    // anchor2: bins 16..31 (mid 24), rates r2/i2
    float Sa = A2a, Sb = A2b, Va = A2a, Vb = A2b;
    acc[24] += A2a + A2b;
    Sa *= r2a; Sb *= r2b; acc[25] = fmaf(Sa + Sb, C1, acc[25]);
    Sa *= r2a; Sb *= r2b; acc[26] = fmaf(Sa + Sb, C2, acc[26]);
    Sa *= r2a; Sb *= r2b; acc[27] = fmaf(Sa + Sb, C3, acc[27]);
    Sa *= r2a; Sb *= r2b; acc[28] = fmaf(Sa + Sb, C4, acc[28]);
    Sa *= r2a; Sb *= r2b; acc[29] = fmaf(Sa + Sb, C5, acc[29]);
    Sa *= r2a; Sb *= r2b; acc[30] = fmaf(Sa + Sb, C6, acc[30]);
    Sa *= r2a; Sb *= r2b; acc[31] = fmaf(Sa + Sb, C7, acc[31]);
    Va *= i2a; Vb *= i2b; acc[23] = fmaf(Va + Vb, C1, acc[23]);
    Va *= i2a; Vb *= i2b; acc[22] = fmaf(Va + Vb, C2, acc[22]);
    Va *= i2a; Vb *= i2b; acc[21] = fmaf(Va + Vb, C3, acc[21]);
    Va *= i2a; Vb *= i2b; acc[20] = fmaf(Va + Vb, C4, acc[20]);
    Va *= i2a; Vb *= i2b; acc[19] = fmaf(Va + Vb, C5, acc[19]);
    Va *= i2a; Vb *= i2b; acc[18] = fmaf(Va + Vb, C6, acc[18]);
    Va *= i2a; Vb *= i2b; acc[17] = fmaf(Va + Vb, C7, acc[17]);
    Va *= i2a; Vb *= i2b; acc[16] = fmaf(Va + Vb, C8, acc[16]);
}

// ---------- pass 2: gather histogram, 32 bins/wave, wave-pairs split chunk ----
// Waves {0,1} cover bins {0-31, 32-63} on the chunk's first half; waves {2,3}
// the second half. Points processed in interleaved pairs (ILP). 1-deep load
// prefetch (R9). No fence/fused finalize (R8 paradox, fixed R10).
// launch_bounds (256,6): 85-VGPR budget (no spill at 52) + 6 blocks/CU for
// latency hiding — R15 showed (256,4) leaves ~30% stall at 31% occupancy.
__global__ __launch_bounds__(256, 6) void hist_k(const float4* __restrict__ pred,
                                                 const float4* __restrict__ tgt,
                                                 const float* __restrict__ mmn,
                                                 const float* __restrict__ mmx,
                                                 float* __restrict__ hist) {
    const int blk   = blockIdx.x;
    const int tens  = blk & 1;
    const int batch = (blk >> 1) & (NB - 1);
    const int chunk = blk >> 5;                      // 0..CB-1
    const int wave  = threadIdx.x >> 6, lane = threadIdx.x & 63;
    const int kwb   = 32 * (wave & 1);               // this wave's first bin
    const int pair  = wave >> 1;                     // which half-chunk

    const int F4C = NPB / 4 / CB;                    // 1024 float4 per chunk
    const int F4H = F4C / 2;                         // 512 per half
    const float4* __restrict__ src = (tens ? tgt : pred)
        + (size_t)batch * (NPB / 4) + (size_t)chunk * F4C + (size_t)pair * F4H;

    // issue first data load before the prologue reduction (overlap)
    float4 v = src[lane];

    // lane-parallel reduce of this batch's 64 minmax partials
    float vmin = mmn[batch * MMB + lane];
    float vmax = mmx[batch * MMB + lane];
    #pragma unroll
    for (int o = 1; o < 64; o <<= 1) {
        vmin = fminf(vmin, __shfl_xor(vmin, o));
        vmax = fmaxf(vmax, __shfl_xor(vmax, o));
    }
    const float s64 = 64.0f / (vmax - vmin + EPSF);
    // d = u - (kwb+8) = x*s64 + bk8
    const float bk8 = fmaf(-vmin, s64, -0.5f) - (float)(kwb + 8);

    float acc[32];
    #pragma unroll
    for (int k = 0; k < 32; ++k) acc[k] = 0.0f;

    const int NIT = F4H / 64;                        // 8 wave-iterations
    #pragma unroll 1
    for (int it = 0; it < NIT; ++it) {
        // prefetch next iteration's data; latency hides under the burst
        float4 vn = src[(it < NIT - 1 ? (it + 1) * 64 : 0) + lane];
        pair32(v.x, v.y, s64, bk8, acc);
        pair32(v.z, v.w, s64, bk8, acc);
        v = vn;
    }

    // in-wave reduce: 32 butterflies; lane i keeps bin kwb+i
    float keep = 0.0f;
    #pragma unroll
    for (int i = 0; i < 32; ++i) {
        float t = acc[i];
        #pragma unroll
        for (int o = 1; o < 64; o <<= 1) t += __shfl_xor(t, o);
        if (lane == i) keep = t;
    }
    if (lane < 32)
        unsafeAtomicAdd(&hist[(tens * NB + batch) * NBINS + kwb + lane], keep);
}

// ---------- pass 3: KL (fp32, v_log), tiny ----------
__global__ __launch_bounds__(256) void final_k(const float* __restrict__ hist,
                                               float* __restrict__ out) {
    const int lane = threadIdx.x & 63, wave = threadIdx.x >> 6;
    __shared__ float wacc[4];
    float a = 0.0f;
    for (int b = wave; b < NB; b += 4) {
        float hp = hist[b * NBINS + lane];
        float ht = hist[(NB + b) * NBINS + lane];
        float sp = hp, st = ht;
        #pragma unroll
        for (int o = 1; o < 64; o <<= 1) {
            sp += __shfl_xor(sp, o);
            st += __shfl_xor(st, o);
        }
        float pp = hp / (sp + EPSF);
        float pt = ht / (st + EPSF);
        float term = pt * ((__builtin_amdgcn_logf(pt + EPSF)
                          - __builtin_amdgcn_logf(pp + EPSF)) * LN2);
        #pragma unroll
        for (int o = 1; o < 64; o <<= 1) term += __shfl_xor(term, o);
        a += term;
    }
    if (lane == 0) wacc[wave] = a;
    __syncthreads();
    if (threadIdx.x == 0)
        out[0] = 0.1f * (wacc[0] + wacc[1] + wacc[2] + wacc[3]) / (float)NB;
}

extern "C" void kernel_launch(void* const* d_in, const int* in_sizes, int n_in,
                              void* d_out, int out_size, void* d_ws, size_t ws_size,
                              hipStream_t stream) {
    const float* pred = (const float*)d_in[0];
    const float* tgt  = (const float*)d_in[1];
    float* mmn  = (float*)d_ws;
    float* mmx  = mmn + NB * MMB;
    float* hist = mmx + NB * MMB;
    float* out  = (float*)d_out;

    minmax_k<<<NB * MMB, 256, 0, stream>>>((const float4*)tgt, mmn, mmx, hist);
    hist_k  <<<2 * NB * CB, 256, 0, stream>>>((const float4*)pred, (const float4*)tgt,
                                              mmn, mmx, hist);
    final_k <<<1, 256, 0, stream>>>(hist, out);
}

// Round 17
// 112.942 us; speedup vs baseline: 1.0346x; 1.0346x over previous
//
#include <hip/hip_runtime.h>
#include <math.h>

// Problem constants
#define NB    16            // batches
#define NPB   (512*512)     // elements per batch
#define NBINS 64
#define MMB   64            // minmax blocks per batch (grid 1024 = 4/CU)
#define CB    64            // hist chunks per (tensor,batch) -> grid 2*16*64 = 2048
#define EPSF  1e-8f
#define QF    0.84932180517f   // sqrt(0.5*log2(e)); exp(-d^2/2) = exp2(-(q*d)^2)
#define L2E   1.44269504089f   // log2(e)
#define LN2   0.69314718056f
#define K16   1.12535175e-7f   // e^-16 (anchor-2 rate adjust)
#define K16I  8886110.5f       // e^+16

// ws layout: mmn[1024] | mmx[1024] | hist[2][16][64]
// R17 = exact revert to R13 (best measured: 113.5 us total, hist 44.1 us,
// VGPR 48, no spill). R14 (,8 spill), R15 (pair ILP neutral), R16 (,6 slight
// spill) all confirmed the neighborhood is flat-to-worse.

// ---------- pass 1: per-batch block-level min/max (also zeroes hist) ----------
__global__ __launch_bounds__(256) void minmax_k(const float4* __restrict__ tgt,
                                                float* __restrict__ mmn,
                                                float* __restrict__ mmx,
                                                float* __restrict__ hist) {
    const int batch = blockIdx.x / MMB, sub = blockIdx.x % MMB;
    if (sub == 0 && threadIdx.x < 128) {
        const int tens = threadIdx.x >> 6, lane = threadIdx.x & 63;
        hist[(tens * NB + batch) * NBINS + lane] = 0.0f;
    }

    const int F4 = NPB / 4 / MMB;              // 1024 float4 per block
    const float4* p = tgt + (size_t)batch * (NPB / 4) + (size_t)sub * F4;
    float mn = 3.4e38f, mx = -3.4e38f;
    #pragma unroll
    for (int i = 0; i < F4 / 256; ++i) {       // 4 iterations
        float4 v = p[i * 256 + threadIdx.x];
        mn = fminf(mn, fminf(fminf(v.x, v.y), fminf(v.z, v.w)));
        mx = fmaxf(mx, fmaxf(fmaxf(v.x, v.y), fmaxf(v.z, v.w)));
    }
    #pragma unroll
    for (int o = 1; o < 64; o <<= 1) {
        mn = fminf(mn, __shfl_xor(mn, o));
        mx = fmaxf(mx, __shfl_xor(mx, o));
    }
    __shared__ float smn[4], smx[4];
    const int wave = threadIdx.x >> 6, lane = threadIdx.x & 63;
    if (lane == 0) { smn[wave] = mn; smx[wave] = mx; }
    __syncthreads();
    if (threadIdx.x == 0) {
        mmn[blockIdx.x] = fminf(fminf(smn[0], smn[1]), fminf(smn[2], smn[3]));
        mmx[blockIdx.x] = fmaxf(fmaxf(smx[0], smx[1]), fmaxf(smx[2], smx[3]));
    }
}

// ---------- per-point update of 32 bins via two anchors sharing r/ri ----------
// d = u - (kwbase+8): anchor1 at bin kwbase+8 (covers bins 0..15 of the
// wave's 32), anchor2 at kwbase+24 (covers 16..31), E(m+i) = A * rho^i * C_i
// with C_i = e^{-i^2/2} literals folded into the accumulate FMA.
// rho for anchor2 = r*e^-16 (2 muls; exp2s shared). d clamped to [-30,46]:
// outside, both A==0 before any rho power can overflow (max ~9e19 finite),
// so far points contribute exactly 0 (true contribution < e^-19).
__device__ __forceinline__ void point32(float xin, float s64, float bk8,
                                        float* __restrict__ acc) {
    const float C1 = 0.60653065971f,    C2 = 0.13533528324f,
                C3 = 0.01110899654f,    C4 = 3.35462627903e-4f,
                C5 = 3.72665317208e-6f, C6 = 1.52299797447e-8f,
                C7 = 2.28973484833e-11f, C8 = 1.26641655490e-14f;
    float d   = fmaf(xin, s64, bk8);
    float dc  = __builtin_amdgcn_fmed3f(d, -30.0f, 46.0f);
    float x   = dc * L2E;
    float r   = __builtin_amdgcn_exp2f(x);
    float ri  = __builtin_amdgcn_exp2f(-x);
    float t1  = dc * QF;
    float A1  = __builtin_amdgcn_exp2f(-(t1 * t1));
    float t2  = fmaf(dc, QF, -16.0f * QF);
    float A2  = __builtin_amdgcn_exp2f(-(t2 * t2));
    float r2  = r * K16;
    float ri2 = ri * K16I;
    // anchor1: bins 0..15 (mid 8)
    float T = A1, U = A1;
    acc[8] += A1;
    T *= r;  acc[9]  = fmaf(T, C1, acc[9]);
    T *= r;  acc[10] = fmaf(T, C2, acc[10]);
    T *= r;  acc[11] = fmaf(T, C3, acc[11]);
    T *= r;  acc[12] = fmaf(T, C4, acc[12]);
    T *= r;  acc[13] = fmaf(T, C5, acc[13]);
    T *= r;  acc[14] = fmaf(T, C6, acc[14]);
    T *= r;  acc[15] = fmaf(T, C7, acc[15]);
    U *= ri; acc[7]  = fmaf(U, C1, acc[7]);
    U *= ri; acc[6]  = fmaf(U, C2, acc[6]);
    U *= ri; acc[5]  = fmaf(U, C3, acc[5]);
    U *= ri; acc[4]  = fmaf(U, C4, acc[4]);
    U *= ri; acc[3]  = fmaf(U, C5, acc[3]);
    U *= ri; acc[2]  = fmaf(U, C6, acc[2]);
    U *= ri; acc[1]  = fmaf(U, C7, acc[1]);
    U *= ri; acc[0]  = fmaf(U, C8, acc[0]);
    // anchor2: bins 16..31 (mid 24), rate r2/ri2
    float S = A2, V = A2;
    acc[24] += A2;
    S *= r2;  acc[25] = fmaf(S, C1, acc[25]);
    S *= r2;  acc[26] = fmaf(S, C2, acc[26]);
    S *= r2;  acc[27] = fmaf(S, C3, acc[27]);
    S *= r2;  acc[28] = fmaf(S, C4, acc[28]);
    S *= r2;  acc[29] = fmaf(S, C5, acc[29]);
    S *= r2;  acc[30] = fmaf(S, C6, acc[30]);
    S *= r2;  acc[31] = fmaf(S, C7, acc[31]);
    V *= ri2; acc[23] = fmaf(V, C1, acc[23]);
    V *= ri2; acc[22] = fmaf(V, C2, acc[22]);
    V *= ri2; acc[21] = fmaf(V, C3, acc[21]);
    V *= ri2; acc[20] = fmaf(V, C4, acc[20]);
    V *= ri2; acc[19] = fmaf(V, C5, acc[19]);
    V *= ri2; acc[18] = fmaf(V, C6, acc[18]);
    V *= ri2; acc[17] = fmaf(V, C7, acc[17]);
    V *= ri2; acc[16] = fmaf(V, C8, acc[16]);
}

// ---------- pass 2: gather histogram, 32 bins/wave, wave-pairs split chunk ----
// Waves {0,1} cover bins {0-31, 32-63} on the chunk's first half; waves {2,3}
// the second half -> each point processed 2x. 1-deep load prefetch (R9).
// No fence/fused finalize (R8 paradox: per-block fence+atomic serialized
// ~60cyc/block and scaled with grid; fixed in R10).
__global__ __launch_bounds__(256, 4) void hist_k(const float4* __restrict__ pred,
                                                 const float4* __restrict__ tgt,
                                                 const float* __restrict__ mmn,
                                                 const float* __restrict__ mmx,
                                                 float* __restrict__ hist) {
    const int blk   = blockIdx.x;
    const int tens  = blk & 1;
    const int batch = (blk >> 1) & (NB - 1);
    const int chunk = blk >> 5;                      // 0..CB-1
    const int wave  = threadIdx.x >> 6, lane = threadIdx.x & 63;
    const int kwb   = 32 * (wave & 1);               // this wave's first bin
    const int pair  = wave >> 1;                     // which half-chunk

    const int F4C = NPB / 4 / CB;                    // 1024 float4 per chunk
    const int F4H = F4C / 2;                         // 512 per half
    const float4* __restrict__ src = (tens ? tgt : pred)
        + (size_t)batch * (NPB / 4) + (size_t)chunk * F4C + (size_t)pair * F4H;

    // issue first data load before the prologue reduction (overlap)
    float4 v = src[lane];

    // lane-parallel reduce of this batch's 64 minmax partials
    float vmin = mmn[batch * MMB + lane];
    float vmax = mmx[batch * MMB + lane];
    #pragma unroll
    for (int o = 1; o < 64; o <<= 1) {
        vmin = fminf(vmin, __shfl_xor(vmin, o));
        vmax = fmaxf(vmax, __shfl_xor(vmax, o));
    }
    const float s64 = 64.0f / (vmax - vmin + EPSF);
    // d = u - (kwb+8) = x*s64 + bk8
    const float bk8 = fmaf(-vmin, s64, -0.5f) - (float)(kwb + 8);

    float acc[32];
    #pragma unroll
    for (int k = 0; k < 32; ++k) acc[k] = 0.0f;

    const int NIT = F4H / 64;                        // 8 wave-iterations
    #pragma unroll 1
    for (int it = 0; it < NIT; ++it) {
        // prefetch next iteration's data; latency hides under the burst
        float4 vn = src[(it < NIT - 1 ? (it + 1) * 64 : 0) + lane];
        point32(v.x, s64, bk8, acc);
        point32(v.y, s64, bk8, acc);
        point32(v.z, s64, bk8, acc);
        point32(v.w, s64, bk8, acc);
        v = vn;
    }

    // in-wave reduce: 32 butterflies; lane i keeps bin kwb+i
    float keep = 0.0f;
    #pragma unroll
    for (int i = 0; i < 32; ++i) {
        float t = acc[i];
        #pragma unroll
        for (int o = 1; o < 64; o <<= 1) t += __shfl_xor(t, o);
        if (lane == i) keep = t;
    }
    if (lane < 32)
        unsafeAtomicAdd(&hist[(tens * NB + batch) * NBINS + kwb + lane], keep);
}

// ---------- pass 3: KL (fp32, v_log), tiny ----------
__global__ __launch_bounds__(256) void final_k(const float* __restrict__ hist,
                                               float* __restrict__ out) {
    const int lane = threadIdx.x & 63, wave = threadIdx.x >> 6;
    __shared__ float wacc[4];
    float a = 0.0f;
    for (int b = wave; b < NB; b += 4) {
        float hp = hist[b * NBINS + lane];
        float ht = hist[(NB + b) * NBINS + lane];
        float sp = hp, st = ht;
        #pragma unroll
        for (int o = 1; o < 64; o <<= 1) {
            sp += __shfl_xor(sp, o);
            st += __shfl_xor(st, o);
        }
        float pp = hp / (sp + EPSF);
        float pt = ht / (st + EPSF);
        float term = pt * ((__builtin_amdgcn_logf(pt + EPSF)
                          - __builtin_amdgcn_logf(pp + EPSF)) * LN2);
        #pragma unroll
        for (int o = 1; o < 64; o <<= 1) term += __shfl_xor(term, o);
        a += term;
    }
    if (lane == 0) wacc[wave] = a;
    __syncthreads();
    if (threadIdx.x == 0)
        out[0] = 0.1f * (wacc[0] + wacc[1] + wacc[2] + wacc[3]) / (float)NB;
}

extern "C" void kernel_launch(void* const* d_in, const int* in_sizes, int n_in,
                              void* d_out, int out_size, void* d_ws, size_t ws_size,
                              hipStream_t stream) {
    const float* pred = (const float*)d_in[0];
    const float* tgt  = (const float*)d_in[1];
    float* mmn  = (float*)d_ws;
    float* mmx  = mmn + NB * MMB;
    float* hist = mmx + NB * MMB;
    float* out  = (float*)d_out;

    minmax_k<<<NB * MMB, 256, 0, stream>>>((const float4*)tgt, mmn, mmx, hist);
    hist_k  <<<2 * NB * CB, 256, 0, stream>>>((const float4*)pred, (const float4*)tgt,
                                              mmn, mmx, hist);
    final_k <<<1, 256, 0, stream>>>(hist, out);
}